// Round 3
// baseline (176.326 us; speedup 1.0000x reference)
//
#include <hip/hip_runtime.h>

// DWT2d db4 — direct global->register row pass (no x staging, no DMA drain),
// single barrier, LDS only for the lo/hi intermediate. TI=4, XCD-stripe grid.
// x: (96, 512, 512) fp32 -> out: (96*4, 256, 256) fp32
// out[bc*4+s][i][j] = sum_{p,q} x[bc][(2i+p)%512][(2j+q)%512] * fH[s][p]*fW[s][q]
//
// Rationale: x is fully L3-resident (FETCH 70MB < 100MB input) and each x float
// is reused only 3x within a wave-contiguous window -> LDS staging of x was
// pure latency (DMA + vmcnt(0) dead-wait + extra barrier). Row pass now loads
// x directly: lane t reads cols 4t..4t+11 of one row = 3 float4 loads,
// lane-consecutive = fully coalesced; L1 serves the 3x overlap.

#define TI 4                // output rows per block
#define TJ 64               // output cols per block
#define PR (2*TI + 6)       // 14 patch rows
#define HH 512
#define WW 512

__global__ __launch_bounds__(256)
void dwt2d_db4_kernel(const float* __restrict__ x,
                      const float* __restrict__ dec,
                      float* __restrict__ out) {
    __shared__ __align__(16) float sm_lo[PR][TJ];   // 3584 B
    __shared__ __align__(16) float sm_hi[PR][TJ];   // 3584 B  -> total 7168 B

    const int tid = threadIdx.x;

    // XCD-stripe mapping: block n -> XCD n&7 (hardware round-robin).
    // XCD x owns it-range [8x, 8x+8) for every bc: per-image stripe of
    // 64+6 input rows (143 KB) stays hot in that XCD's L2 across jt/bc.
    const int n  = blockIdx.x;
    const int m  = n >> 3;
    const int jt = m & 3;                        // 0..3
    const int it = (n & 7) * 8 + ((m >> 2) & 7); // 0..63
    const int bc = m >> 5;                       // 0..95

    const int rowBase = it * (2 * TI);
    const int colBase = jt * (2 * TJ);

    float flo[8], fhi[8];
#pragma unroll
    for (int k = 0; k < 8; ++k) { flo[k] = dec[k]; fhi[k] = dec[8 + k]; }

    const float* xb = x + (size_t)bc * HH * WW;

    // ---- Phase B: row pass, direct from global. Task (r,t) -> outputs
    //      (2t,2t+1) of patch row r. Lanes 0..31 cover one row contiguously:
    //      each float4 load is a 512 B/half-wave coalesced read. ----
    for (int task = tid; task < PR * (TJ / 2); task += 256) {   // 448 tasks
        int r = task >> 5;
        int t = task & 31;
        int gr = rowBase + r;          if (gr >= HH) gr -= HH;
        int c0 = colBase + 4 * t;      // granule-aligned; wrap per granule
        int c1 = c0 + 4;               if (c1 >= WW) c1 -= WW;
        int c2 = c0 + 8;               if (c2 >= WW) c2 -= WW;
        const float* xr = xb + gr * WW;
        float4 v0 = *(const float4*)(xr + c0);
        float4 v1 = *(const float4*)(xr + c1);
        float4 v2 = *(const float4*)(xr + c2);
        float w[12] = { v0.x, v0.y, v0.z, v0.w,
                        v1.x, v1.y, v1.z, v1.w,
                        v2.x, v2.y, v2.z, v2.w };
        float lo0 = 0.f, hi0 = 0.f, lo1 = 0.f, hi1 = 0.f;
#pragma unroll
        for (int q = 0; q < 8; ++q) {
            lo0 += w[q]     * flo[q];
            hi0 += w[q]     * fhi[q];
            lo1 += w[q + 2] * flo[q];
            hi1 += w[q + 2] * fhi[q];
        }
        *(float2*)&sm_lo[r][2 * t] = make_float2(lo0, lo1);
        *(float2*)&sm_hi[r][2 * t] = make_float2(hi0, hi1);
    }
    __syncthreads();

    // ---- Phase C: col pass. Thread -> 1 output pixel, all 4 subbands. ----
    {
        int i = tid >> 6;             // 0..3
        int j = tid & 63;             // 0..63
        float ll = 0.f, lh = 0.f, hl = 0.f, hh = 0.f;
#pragma unroll
        for (int p = 0; p < 8; ++p) {
            float a = sm_lo[2 * i + p][j];
            float b = sm_hi[2 * i + p][j];
            float cl = flo[p], ch = fhi[p];
            ll += a * cl; lh += a * ch;
            hl += b * cl; hh += b * ch;
        }
        int oi = it * TI + i;
        int oj = jt * TJ + j;
        size_t base = ((size_t)(bc * 4) * 256 + oi) * 256 + oj;
        __builtin_nontemporal_store(ll, &out[base]);
        __builtin_nontemporal_store(lh, &out[base + 1 * 65536]);
        __builtin_nontemporal_store(hl, &out[base + 2 * 65536]);
        __builtin_nontemporal_store(hh, &out[base + 3 * 65536]);
    }
}

extern "C" void kernel_launch(void* const* d_in, const int* in_sizes, int n_in,
                              void* d_out, int out_size, void* d_ws, size_t ws_size,
                              hipStream_t stream) {
    const float* x   = (const float*)d_in[0];
    const float* dec = (const float*)d_in[1];
    float* out = (float*)d_out;

    dim3 grid(4 * 64 * 96);              // 24576 blocks, 1D (XCD-stripe mapped)
    dim3 block(256);
    dwt2d_db4_kernel<<<grid, block, 0, stream>>>(x, dec, out);
}